// Round 14
// baseline (712.001 us; speedup 1.0000x reference)
//
#include <hip/hip_runtime.h>
#include <hip/hip_bf16.h>

#define BB_ 16
#define TT_ 96
#define NN 512
#define DD 128
#define MM 1196
#define KK 8
#define HID 65536
#define TP 97
#define TPAD 128

typedef __attribute__((ext_vector_type(8))) short short8v;
typedef __attribute__((ext_vector_type(4))) float f32x4;

__device__ __forceinline__ float gelu_exact(float x) {
    return 0.5f * x * (1.0f + erff(x * 0.70710678118654752f));
}
__device__ __forceinline__ unsigned rne16(float f) {
    unsigned u = __float_as_uint(f);
    return (u + 0x7fffu + ((u >> 16) & 1u)) >> 16;
}
__device__ __forceinline__ float bf2f(short s) {
    return __uint_as_float(((unsigned)(unsigned short)s) << 16);
}
// split f32 -> bf16 hi + bf16 lo (hi = rne(x), lo = rne(x - hi))
__device__ __forceinline__ void split2(float x, short& hi, short& lo) {
    unsigned h = rne16(x);
    hi = (short)h;
    float hf = __uint_as_float(h << 16);
    lo = (short)rne16(x - hf);
}
__device__ __forceinline__ void gload_lds16(const void* g, void* l) {
    __builtin_amdgcn_global_load_lds((const __attribute__((address_space(1))) void*)g,
                                     (__attribute__((address_space(3))) void*)l, 16, 0, 0);
}
__device__ __forceinline__ short8v pack8(float4 a, float4 b) {
    short t[8];
    t[0] = (short)rne16(a.x); t[1] = (short)rne16(a.y);
    t[2] = (short)rne16(a.z); t[3] = (short)rne16(a.w);
    t[4] = (short)rne16(b.x); t[5] = (short)rne16(b.y);
    t[6] = (short)rne16(b.z); t[7] = (short)rne16(b.w);
    return *(short8v*)t;
}
// k2 swizzle for 32-elem (4-chunk) rows: period-16 bank-complete (r7-proven)
__device__ __forceinline__ int swz32(int row) {
    return (row & 3) ^ ((row >> 2) & 3);
}
// stage a 128x128 bf16 tile (row-major, 128-short rows) from global into XOR-swizzled LDS
__device__ __forceinline__ void stage_tile_sw(const short* g, short* lds, int tid) {
    #pragma unroll
    for (int j = 0; j < 8; ++j) {
        int row = j * 16 + (tid >> 4);
        int csrc = (tid & 15) ^ (row & 7);
        gload_lds16(g + row * 128 + csrc * 8, lds + j * 2048 + tid * 8);
    }
}
// fragment read from swizzled 128x128 tile: row, k-iter kk (0..3), lk (0..3)
__device__ __forceinline__ short8v frag_ld(const short* lds, int row, int kk, int lk) {
    return *(const short8v*)&lds[row * 128 + (((kk << 2) + lk) ^ (row & 7)) * 8];
}

// K0: pw_w f32 -> (hi, lo) bf16 pair
__global__ __launch_bounds__(256) void k0_cvt2(const float* __restrict__ src,
                                               short* __restrict__ hi, short* __restrict__ lo) {
    size_t i = ((size_t)blockIdx.x * 256 + threadIdx.x) * 8;
    float4 a = *(const float4*)(src + i);
    float4 b = *(const float4*)(src + i + 4);
    short h[8], l[8];
    split2(a.x, h[0], l[0]); split2(a.y, h[1], l[1]);
    split2(a.z, h[2], l[2]); split2(a.w, h[3], l[3]);
    split2(b.x, h[4], l[4]); split2(b.y, h[5], l[5]);
    split2(b.z, h[6], l[6]); split2(b.w, h[7], l[7]);
    *(short8v*)(hi + i) = *(short8v*)h;
    *(short8v*)(lo + i) = *(short8v*)l;
}

// K1: depthwise conv + bias + exact gelu -> xct hi/lo bf16, layout [b][t][n], zero-padded t>=97
__global__ __launch_bounds__(256) void k1_conv(const float* __restrict__ x,
                                               const float* __restrict__ dw_w,
                                               const float* __restrict__ dw_b,
                                               short* __restrict__ xh,
                                               short* __restrict__ xl) {
    int b = blockIdx.y, n0 = blockIdx.x * 64;
    __shared__ float xs[96][64];
    __shared__ float ws[64][12];
    __shared__ float bs[64];
    int tid = threadIdx.x;
    for (int j = tid; j < 96 * 64; j += 256) {
        int t = j / 64, n = j % 64;
        xs[t][n] = x[(size_t)(b * TT_ + t) * NN + n0 + n];
    }
    for (int j = tid; j < 64 * 12; j += 256) {
        int n = j / 12, k = j % 12;
        ws[n][k] = dw_w[(size_t)(n0 + n) * 12 + k];
    }
    if (tid < 64) bs[tid] = dw_b[n0 + tid];
    __syncthreads();
    int n = tid % 64, g = tid / 64;
    for (int t = g; t < TP; t += 4) {
        float acc = bs[n];
        #pragma unroll
        for (int k = 0; k < 12; ++k) {
            int ti = t - 6 + k;
            if (ti >= 0 && ti < 96) acc += xs[ti][n] * ws[n][k];
        }
        float v = gelu_exact(acc);
        short h, l;
        split2(v, h, l);
        size_t idx = ((size_t)b * TPAD + t) * NN + n0 + n;
        xh[idx] = h; xl[idx] = l;
    }
    for (int t = TP + g; t < TPAD; t += 4) {
        size_t idx = ((size_t)b * TPAD + t) * NN + n0 + n;
        xh[idx] = 0; xl[idx] = 0;
    }
}

// K2: split-bf16 3-pass MFMA GEMM, BK=32, 32 KB LDS -> 5 blocks/CU (160 KiB exactly).
// 1x4 wave layout: wave w owns o-strip [w*32, w*32+32) x ALL t. t-frag 7 (t=112..127,
// identically zero) dropped with COMPILE-TIME bounds (n<7). Epilogue: per-wave rows,
// float4 direct store. XCD-aware 1-D grid: xcd owns o-groups [xcd*64, xcd*64+64).
template <bool PRE>
__global__ __launch_bounds__(256, 5) void k2_split(const float* __restrict__ pw_w,
                                                   const short* __restrict__ aH,
                                                   const short* __restrict__ aL,
                                                   const float* __restrict__ pw_b,
                                                   const short* __restrict__ bH,
                                                   const short* __restrict__ bL,
                                                   float* __restrict__ q_pre) {
    int wgid = blockIdx.x;
    int xcd = wgid & 7;
    int r = wgid >> 3;
    int b = r & 15;
    int o0 = (xcd * 64 + (r >> 4)) * 128;
    __shared__ short AsH[4096], AsL[4096], BsH[4096], BsL[4096];
    int tid = threadIdx.x;
    int l = tid & 63, w = tid >> 6;
    int lrow = l & 15, lk = l >> 4;
    const short* bHb = bH + (size_t)b * TPAD * NN;
    const short* bLb = bL + (size_t)b * TPAD * NN;

    f32x4 acc[2][7];
    #pragma unroll
    for (int m = 0; m < 2; ++m)
        #pragma unroll
        for (int n = 0; n < 7; ++n) acc[m][n] = (f32x4){0.f, 0.f, 0.f, 0.f};

    for (int it = 0; it < 16; ++it) {
        int k0 = it * 32;
        #pragma unroll
        for (int j = 0; j < 2; ++j) {
            int row = j * 64 + (tid >> 2);
            int c = tid & 3;
            int sc = c ^ swz32(row);           // pre-swizzled source chunk
            int dofs = (j * 256 + tid) * 8;    // linear LDS dest
            // B rows 112..127 are never read (zero t-frag dropped) -> skip staging
            if (!(j == 1 && (tid >> 2) >= 48)) {
                gload_lds16(bHb + (size_t)row * NN + k0 + sc * 8, &BsH[dofs]);
                gload_lds16(bLb + (size_t)row * NN + k0 + sc * 8, &BsL[dofs]);
            }
            if constexpr (PRE) {
                gload_lds16(aH + (size_t)(o0 + row) * 512 + k0 + sc * 8, &AsH[dofs]);
                gload_lds16(aL + (size_t)(o0 + row) * 512 + k0 + sc * 8, &AsL[dofs]);
            } else {
                const float* src = pw_w + (size_t)(o0 + row) * 512 + k0 + c * 8;
                float4 v0 = *(const float4*)(src);
                float4 v1 = *(const float4*)(src + 4);
                short h[8], lo[8];
                split2(v0.x, h[0], lo[0]); split2(v0.y, h[1], lo[1]);
                split2(v0.z, h[2], lo[2]); split2(v0.w, h[3], lo[3]);
                split2(v1.x, h[4], lo[4]); split2(v1.y, h[5], lo[5]);
                split2(v1.z, h[6], lo[6]); split2(v1.w, h[7], lo[7]);
                int didx = row * 32 + (c ^ swz32(row)) * 8;
                *(short8v*)&AsH[didx] = *(short8v*)h;
                *(short8v*)&AsL[didx] = *(short8v*)lo;
            }
        }
        __syncthreads();
        short8v ah[2], al[2];
        #pragma unroll
        for (int m = 0; m < 2; ++m) {
            int row = w * 32 + m * 16 + lrow;
            int idx = row * 32 + (lk ^ swz32(row)) * 8;
            ah[m] = *(const short8v*)&AsH[idx];
            al[m] = *(const short8v*)&AsL[idx];
        }
        #pragma unroll
        for (int n = 0; n < 7; ++n) {
            int row = n * 16 + lrow;
            int idx = row * 32 + (lk ^ swz32(row)) * 8;
            short8v bh = *(const short8v*)&BsH[idx];
            short8v bl = *(const short8v*)&BsL[idx];
            #pragma unroll
            for (int m = 0; m < 2; ++m) {
                acc[m][n] = __builtin_amdgcn_mfma_f32_16x16x32_bf16(ah[m], bh, acc[m][n], 0, 0, 0);
                acc[m][n] = __builtin_amdgcn_mfma_f32_16x16x32_bf16(ah[m], bl, acc[m][n], 0, 0, 0);
                acc[m][n] = __builtin_amdgcn_mfma_f32_16x16x32_bf16(al[m], bh, acc[m][n], 0, 0, 0);
            }
        }
        __syncthreads();
    }
    // epilogue: bias + exact gelu + mask t<97 + mean over t; per-wave rows, direct store
    #pragma unroll
    for (int m = 0; m < 2; ++m) {
        float s4[4];
        #pragma unroll
        for (int reg = 0; reg < 4; ++reg) {
            int o_loc = w * 32 + m * 16 + lk * 4 + reg;
            float bias = pw_b[o0 + o_loc];
            float s = 0.f;
            #pragma unroll
            for (int n = 0; n < 7; ++n) {
                int t = n * 16 + lrow;
                if (t < TP) s += gelu_exact(acc[m][n][reg] + bias);
            }
            s += __shfl_xor(s, 1, 64);
            s += __shfl_xor(s, 2, 64);
            s += __shfl_xor(s, 4, 64);
            s += __shfl_xor(s, 8, 64);
            s4[reg] = s * (1.0f / 97.0f);
        }
        if (lrow == 0) {
            int o_loc = w * 32 + m * 16 + lk * 4;
            *(float4*)(q_pre + (size_t)b * HID + o0 + o_loc) = make_float4(s4[0], s4[1], s4[2], s4[3]);
        }
    }
}

// K3: LayerNorm over D=128 per row; writes q (second output)
__global__ __launch_bounds__(256) void k3_ln(const float* __restrict__ q_pre,
                                             const float* __restrict__ g,
                                             const float* __restrict__ beta,
                                             float* __restrict__ qout) {
    int row = blockIdx.x * 4 + (threadIdx.x >> 6);
    int lane = threadIdx.x & 63;
    const float* src = q_pre + (size_t)row * 128;
    float v0 = src[lane], v1 = src[lane + 64];
    float s = v0 + v1;
    #pragma unroll
    for (int m = 32; m >= 1; m >>= 1) s += __shfl_xor(s, m, 64);
    float mu = s * (1.f / 128.f);
    float d0 = v0 - mu, d1 = v1 - mu;
    float vs = d0 * d0 + d1 * d1;
    #pragma unroll
    for (int m = 32; m >= 1; m >>= 1) vs += __shfl_xor(vs, m, 64);
    float rstd = rsqrtf(vs * (1.f / 128.f) + 1e-5f);
    qout[(size_t)row * 128 + lane] = d0 * rstd * g[lane] + beta[lane];
    qout[(size_t)row * 128 + lane + 64] = d1 * rstd * g[lane + 64] + beta[lane + 64];
}

// K3b: per-b L2 norm of q
__global__ __launch_bounds__(256) void k3b_qnorm(const float* __restrict__ q, float* __restrict__ qnorm) {
    int b = blockIdx.x;
    const float* src = q + (size_t)b * HID;
    float s = 0.f;
    for (int i = threadIdx.x * 4; i < HID; i += 256 * 4) {
        float4 v = *(const float4*)(src + i);
        s += v.x * v.x + v.y * v.y + v.z * v.z + v.w * v.w;
    }
    #pragma unroll
    for (int m = 32; m >= 1; m >>= 1) s += __shfl_xor(s, m, 64);
    __shared__ float red[4];
    if ((threadIdx.x & 63) == 0) red[threadIdx.x >> 6] = s;
    __syncthreads();
    if (threadIdx.x == 0) qnorm[b] = sqrtf(red[0] + red[1] + red[2] + red[3]);
}

// K4: fused (mem row sumsq) + (16 q-dots), m-tile=4, deterministic K-split partials
__global__ __launch_bounds__(256) void k4_sim(const float* __restrict__ mem,
                                              const float* __restrict__ q,
                                              float* __restrict__ sim_part,
                                              float* __restrict__ nrm_part) {
    int m0 = blockIdx.x * 4;
    int isp = blockIdx.y;
    int tid = threadIdx.x;
    float acc[4][16];
    float nr[4] = {0.f, 0.f, 0.f, 0.f};
    #pragma unroll
    for (int a = 0; a < 4; ++a)
        #pragma unroll
        for (int c = 0; c < 16; ++c) acc[a][c] = 0.f;
    int ibase = isp * 16384;
    for (int it = 0; it < 16; ++it) {
        int i = ibase + (it * 256 + tid) * 4;
        float4 mv[4];
        #pragma unroll
        for (int a = 0; a < 4; ++a) {
            mv[a] = *(const float4*)(mem + (size_t)(m0 + a) * HID + i);
            nr[a] += mv[a].x * mv[a].x + mv[a].y * mv[a].y + mv[a].z * mv[a].z + mv[a].w * mv[a].w;
        }
        #pragma unroll
        for (int c = 0; c < 16; ++c) {
            float4 qv = *(const float4*)(q + (size_t)c * HID + i);
            #pragma unroll
            for (int a = 0; a < 4; ++a)
                acc[a][c] += mv[a].x * qv.x + mv[a].y * qv.y + mv[a].z * qv.z + mv[a].w * qv.w;
        }
    }
    __shared__ float red[4][68];
    int wv = tid >> 6, lane = tid & 63;
    #pragma unroll
    for (int a = 0; a < 4; ++a)
        for (int c = 0; c < 17; ++c) {
            float v = (c < 16) ? acc[a][c] : nr[a];
            #pragma unroll
            for (int m = 32; m >= 1; m >>= 1) v += __shfl_xor(v, m, 64);
            if (lane == 0) red[wv][a * 17 + c] = v;
        }
    __syncthreads();
    if (tid < 68) {
        float v = red[0][tid] + red[1][tid] + red[2][tid] + red[3][tid];
        int a = tid / 17, r = tid % 17;
        if (r < 16) sim_part[((size_t)isp * 16 + r) * MM + m0 + a] = v;
        else nrm_part[(size_t)isp * MM + m0 + a] = v;
    }
}

// K5: combine, normalize, mask, diversity, top-8 (tie -> lower index)
__global__ __launch_bounds__(256) void k5_topk(const float* __restrict__ sim_part,
                                               const float* __restrict__ nrm_part,
                                               const float* __restrict__ qnorm,
                                               const int* __restrict__ season_q,
                                               const float* __restrict__ year_q,
                                               const int* __restrict__ mem_season,
                                               const float* __restrict__ mem_year,
                                               int* __restrict__ topk) {
    int b = blockIdx.x;
    int tid = threadIdx.x;
    __shared__ float sadj[MM];
    float nq = fmaxf(qnorm[b], 1e-12f);
    int sq = season_q[b];
    float yq = year_q[b];
    for (int m = tid; m < MM; m += 256) {
        float dot = 0.f, ns = 0.f;
        #pragma unroll
        for (int p = 0; p < 4; ++p) {
            dot += sim_part[((size_t)p * 16 + b) * MM + m];
            ns += nrm_part[(size_t)p * MM + m];
        }
        float nm = fmaxf(sqrtf(ns), 1e-12f);
        float s = dot / (nq * nm);
        if (mem_season[m] != sq) s = -10000.0f;
        float dy = fabsf(yq - mem_year[m]);
        float dv = 1.0f - expf(-dy * 0.5f);
        s *= (0.5f + 0.5f * dv);
        sadj[m] = s;
    }
    __syncthreads();
    __shared__ float rv[4];
    __shared__ int ri[4];
    for (int it = 0; it < 8; ++it) {
        float bv = -INFINITY;
        int bi = -1;
        for (int m = tid; m < MM; m += 256) {
            float v = sadj[m];
            if (v > bv || (v == bv && bi >= 0 && m < bi)) { bv = v; bi = m; }
        }
        #pragma unroll
        for (int msk = 32; msk >= 1; msk >>= 1) {
            float ov = __shfl_xor(bv, msk, 64);
            int oi = __shfl_xor(bi, msk, 64);
            if (oi >= 0 && (ov > bv || (ov == bv && (bi < 0 || oi < bi)))) { bv = ov; bi = oi; }
        }
        int lane = tid & 63, wv = tid >> 6;
        if (lane == 0) { rv[wv] = bv; ri[wv] = bi; }
        __syncthreads();
        if (tid == 0) {
            float fv = rv[0]; int fi = ri[0];
            for (int w = 1; w < 4; ++w)
                if (ri[w] >= 0 && (rv[w] > fv || (rv[w] == fv && (fi < 0 || ri[w] < fi)))) { fv = rv[w]; fi = ri[w]; }
            topk[b * KK + it] = fi;
            sadj[fi] = -INFINITY;
        }
        __syncthreads();
    }
}

// K6w: weight prep — bf16 Wq/Wk/Wv; combined Wc = proj_w@out_proj_w (bf16), bc = proj_w@out_proj_b + proj_b
__global__ __launch_bounds__(256) void k6w(const float* __restrict__ in_w,
                                           const float* __restrict__ ow,
                                           const float* __restrict__ ob,
                                           const float* __restrict__ pw,
                                           const float* __restrict__ pb,
                                           short* __restrict__ WQKV16,
                                           short* __restrict__ WC16,
                                           float* __restrict__ BC) {
    __shared__ float ow_s[16384];
    int tid = threadIdx.x;
    for (int i = tid * 4; i < 16384; i += 1024)
        *(float4*)&ow_s[i] = *(const float4*)&ow[i];
    for (int i = tid * 8; i < 49152; i += 2048) {
        float4 a = *(const float4*)(in_w + i);
        float4 b = *(const float4*)(in_w + i + 4);
        *(short8v*)(WQKV16 + i) = pack8(a, b);
    }
    __syncthreads();
    int d = tid >> 1, j0 = (tid & 1) * 64;
    float accv[64];
    #pragma unroll
    for (int j = 0; j < 64; ++j) accv[j] = 0.f;
    for (int i = 0; i < 128; ++i) {
        float wv = pw[d * 128 + i];
        const float* orow = &ow_s[i * 128 + j0];
        #pragma unroll
        for (int j = 0; j < 64; ++j) accv[j] += wv * orow[j];
    }
    #pragma unroll
    for (int j = 0; j < 64; ++j) WC16[d * 128 + j0 + j] = (short)rne16(accv[j]);
    if (tid < 128) {
        float s = pb[tid];
        for (int i = 0; i < 128; ++i) s += pw[tid * 128 + i] * ob[i];
        BC[tid] = s;
    }
}

// K6q: QH = q @ Wq^T + bq  (per b, 128-row tiles), bf16 out
__global__ __launch_bounds__(256) void k6q(const float* __restrict__ q,
                                           const short* __restrict__ WQKV16,
                                           const float* __restrict__ in_b,
                                           short* __restrict__ QH16) {
    int b = blockIdx.y;
    int n0 = blockIdx.x * 128;
    __shared__ short As[16384], Ws[16384];
    int tid = threadIdx.x;
    int l = tid & 63, w = tid >> 6;
    int wr = w >> 1, wc = w & 1;
    int lrow = l & 15, lk = l >> 4;

    stage_tile_sw(WQKV16, Ws, tid);
    {
        int row = tid >> 1, half = tid & 1;
        const float* src = q + ((size_t)b * NN + n0 + row) * 128 + half * 64;
        #pragma unroll
        for (int cc = 0; cc < 8; ++cc) {
            float4 v0 = *(const float4*)(src + cc * 8);
            float4 v1 = *(const float4*)(src + cc * 8 + 4);
            int chunk = half * 8 + cc;
            *(short8v*)&As[row * 128 + (chunk ^ (row & 7)) * 8] = pack8(v0, v1);
        }
    }
    __syncthreads();
    f32x4 acc[4][4];
    #pragma unroll
    for (int m = 0; m < 4; ++m)
        #pragma unroll
        for (int n = 0; n < 4; ++n) acc[m][n] = (f32x4){0.f, 0.f, 0.f, 0.f};
    #pragma unroll
    for (int kk = 0; kk < 4; ++kk) {
        short8v a[4], bw[4];
        #pragma unroll
        for (int m = 0; m < 4; ++m) a[m] = frag_ld(As, wr * 64 + m * 16 + lrow, kk, lk);
        #pragma unroll
        for (int n = 0; n < 4; ++n) bw[n] = frag_ld(Ws, wc * 64 + n * 16 + lrow, kk, lk);
        #pragma unroll
        for (int m = 0; m < 4; ++m)
            #pragma unroll
            for (int n = 0; n < 4; ++n)
                acc[m][n] = __builtin_amdgcn_mfma_f32_16x16x32_bf16(a[m], bw[n], acc[m][n], 0, 0, 0);
    }
    #pragma unroll
    for (int m = 0; m < 4; ++m)
        #pragma unroll
        for (int n = 0; n < 4; ++n)
            #pragma unroll
            for (int reg = 0; reg < 4; ++reg) {
                int r = wr * 64 + m * 16 + lk * 4 + reg;
                int dco = wc * 64 + n * 16 + lrow;
                QH16[((size_t)b * NN + n0 + r) * 128 + dco] = (short)rne16(acc[m][n][reg] + in_b[dco]);
            }
}

// K6kv: gather kv rows, project with Wk and Wv (shared A-tile), bf16 out
__global__ __launch_bounds__(256) void k6kv(const float* __restrict__ mem,
                                            const int* __restrict__ topk,
                                            const short* __restrict__ WQKV16,
                                            const float* __restrict__ in_b,
                                            short* __restrict__ KH16,
                                            short* __restrict__ VH16) {
    int b = blockIdx.y;
    int n0 = blockIdx.x * 16;
    __shared__ short As[16384], WkS[16384], WvS[16384];
    __shared__ int idx_s[8];
    int tid = threadIdx.x;
    int l = tid & 63, w = tid >> 6;
    int wr = w >> 1, wc = w & 1;
    int lrow = l & 15, lk = l >> 4;
    if (tid < 8) idx_s[tid] = topk[b * 8 + tid];
    stage_tile_sw(WQKV16 + 16384, WkS, tid);
    stage_tile_sw(WQKV16 + 32768, WvS, tid);
    __syncthreads();
    {
        int row = tid >> 1, half = tid & 1;
        int n = n0 + (row >> 3), k = row & 7;
        const float* src = mem + (size_t)idx_s[k] * HID + (size_t)n * 128 + half * 64;
        #pragma unroll
        for (int cc = 0; cc < 8; ++cc) {
            float4 v0 = *(const float4*)(src + cc * 8);
            float4 v1 = *(const float4*)(src + cc * 8 + 4);
            int chunk = half * 8 + cc;
            *(short8v*)&As[row * 128 + (chunk ^ (row & 7)) * 8] = pack8(v0, v1);
        }
    }
    __syncthreads();
    f32x4 ak_[4][4], av_[4][4];
    #pragma unroll
    for (int m = 0; m < 4; ++m)
        #pragma unroll
        for (int n = 0; n < 4; ++n) {
            ak_[m][n] = (f32x4){0.f, 0.f, 0.f, 0.f};
            av_[m][n] = (f32x4){0.f, 0.f, 0.f, 0.f};
        }
    #pragma unroll
    for (int kk = 0; kk < 4; ++kk) {
        short8v a[4], bk[4], bv[4];
        #pragma unroll
        for (int m = 0; m < 4; ++m) a[m] = frag_ld(As, wr * 64 + m * 16 + lrow, kk, lk);
        #pragma unroll
        for (int n = 0; n < 4; ++n) {
            bk[n] = frag_ld(WkS, wc * 64 + n * 16 + lrow, kk, lk);
            bv[n] = frag_ld(WvS, wc * 64 + n * 16 + lrow, kk, lk);
        }
        #pragma unroll
        for (int m = 0; m < 4; ++m)
            #pragma unroll
            for (int n = 0; n < 4; ++n) {
                ak_[m][n] = __builtin_amdgcn_mfma_f32_16x16x32_bf16(a[m], bk[n], ak_[m][n], 0, 0, 0);
                av_[m][n] = __builtin_amdgcn_mfma_f32_16x16x32_bf16(a[m], bv[n], av_[m][n], 0, 0, 0);
            }
    }
    #pragma unroll
    for (int m = 0; m < 4; ++m)
        #pragma unroll
        for (int n = 0; n < 4; ++n)
            #pragma unroll
            for (int reg = 0; reg < 4; ++reg) {
                int r = wr * 64 + m * 16 + lk * 4 + reg;
                int dco = wc * 64 + n * 16 + lrow;
                int nl = r >> 3, k = r & 7;
                size_t o = (((size_t)b * NN + n0 + nl) * 8 + k) * 128 + dco;
                KH16[o] = (short)rne16(ak_[m][n][reg] + in_b[128 + dco]);
                VH16[o] = (short)rne16(av_[m][n][reg] + in_b[256 + dco]);
            }
}

// K6s: scores + softmax + ctx. Vectorized: each lane owns 4 consecutive d (short4 = 8B loads);
// head = octet (8 lanes x 4 d = 32 d); reduction = 3-step octet butterfly.
__global__ __launch_bounds__(256) void k6s(const short* __restrict__ QH16,
                                           const short* __restrict__ KH16,
                                           const short* __restrict__ VH16,
                                           short* __restrict__ CTX16) {
    int b = blockIdx.y;
    int n = blockIdx.x * 8 + (threadIdx.x >> 5);
    int dh = threadIdx.x & 31;
    int d0 = dh * 4;
    size_t qbase = ((size_t)b * NN + n) * 128;
    size_t kvbase = qbase * 8;
    short4 q4 = *(const short4*)(QH16 + qbase + d0);
    float q0 = bf2f(q4.x), q1 = bf2f(q4.y), q2 = bf2f(q4.z), q3 = bf2f(q4.w);
    float sc[8];
    #pragma unroll
    for (int k = 0; k < 8; ++k) {
        short4 k4 = *(const short4*)(KH16 + kvbase + k * 128 + d0);
        float p = q0 * bf2f(k4.x) + q1 * bf2f(k4.y) + q2 * bf2f(k4.z) + q3 * bf2f(k4.w);
        p += __shfl_xor(p, 1, 32);
        p += __shfl_xor(p, 2, 32);
        p += __shfl_xor(p, 4, 32);
        sc[k] = p * 0.17677669529663687f;
    }
    float mx = sc[0];
    #pragma unroll
    for (int k = 1; k < 8; ++k) mx = fmaxf(mx, sc[k]);
    float den = 0.f;
    #pragma unroll
    for (int k = 0; k < 8; ++k) { sc[k] = expf(sc[k] - mx); den += sc[k]; }
    float inv = 1.0f / den;
    float c0 = 0.f, c1 = 0.f, c2 = 0.f, c3 = 0.f;
    #pragma unroll
    for (int k = 0; k < 8; ++k) {
        short4 v4 = *(const short4*)(VH16 + kvbase + k * 128 + d0);
        c0 += sc[k] * bf2f(v4.x);
        c1 += sc[k] * bf2f(v4.y);
        c2 += sc[k] * bf2f(v4.z);
        c3 += sc[k] * bf2f(v4.w);
    }
    short4 o4;
    o4.x = (short)rne16(c0 * inv);
    o4.y = (short)rne16(c1 * inv);
    o4.z = (short)rne16(c2 * inv);
    o4.w = (short)rne16(c3 * inv);
    *(short4*)(CTX16 + qbase + d0) = o4;
}

// K6f: out = ctx @ Wc^T + bc (128-row tiles over all 8192 rows), f32 out
__global__ __launch_bounds__(256) void k6f(const short* __restrict__ CTX16,
                                           const short* __restrict__ WC16,
                                           const float* __restrict__ BC,
                                           float* __restrict__ out) {
    int r0 = blockIdx.x * 128;
    __shared__ short As[16384], Ws[16384];
    int tid = threadIdx.x;
    int l = tid & 63, w = tid >> 6;
    int wr = w >> 1, wc = w & 1;
    int lrow = l & 15, lk = l >> 4;
    stage_tile_sw(CTX16 + (size_t)r0 * 128, As, tid);
    stage_tile_sw(WC16, Ws, tid);
    __syncthreads();
    f32x4 acc[4][4];
    #pragma unroll
    for (int m = 0; m < 4; ++m)
        #pragma unroll
        for (int n = 0; n < 4; ++n) acc[m][n] = (f32x4){0.f, 0.f, 0.f, 0.f};
    #pragma unroll
    for (int kk = 0; kk < 4; ++kk) {
        short8v a[4], bw[4];
        #pragma unroll
        for (int m = 0; m < 4; ++m) a[m] = frag_ld(As, wr * 64 + m * 16 + lrow, kk, lk);
        #pragma unroll
        for (int n = 0; n < 4; ++n) bw[n] = frag_ld(Ws, wc * 64 + n * 16 + lrow, kk, lk);
        #pragma unroll
        for (int m = 0; m < 4; ++m)
            #pragma unroll
            for (int n = 0; n < 4; ++n)
                acc[m][n] = __builtin_amdgcn_mfma_f32_16x16x32_bf16(a[m], bw[n], acc[m][n], 0, 0, 0);
    }
    #pragma unroll
    for (int m = 0; m < 4; ++m)
        #pragma unroll
        for (int n = 0; n < 4; ++n)
            #pragma unroll
            for (int reg = 0; reg < 4; ++reg) {
                int r = wr * 64 + m * 16 + lk * 4 + reg;
                int dco = wc * 64 + n * 16 + lrow;
                out[(size_t)(r0 + r) * 128 + dco] = acc[m][n][reg] + BC[dco];
            }
}

// K6 fallback monolith (used only if ws too small for the split attention path)
__global__ __launch_bounds__(256) void k6_attn(const float* __restrict__ mem,
                                               const float* __restrict__ q,
                                               const int* __restrict__ topk,
                                               const float* __restrict__ in_w,
                                               const float* __restrict__ in_b,
                                               const float* __restrict__ ow,
                                               const float* __restrict__ ob,
                                               const float* __restrict__ pw,
                                               const float* __restrict__ pb,
                                               float* __restrict__ out) {
    int b = blockIdx.y;
    int n0 = blockIdx.x * 4;
    int tid = threadIdx.x;
    __shared__ float kv_s[4][8][128];
    __shared__ float kh_s[4][8][128];
    __shared__ float vh_s[4][8][128];
    __shared__ float qin_s[4][128];
    __shared__ float qh_s[4][128];
    __shared__ float ctx_s[4][128];
    __shared__ float o1_s[4][128];
    __shared__ int idx_s[8];
    if (tid < 8) idx_s[tid] = topk[b * 8 + tid];
    __syncthreads();
    for (int j = tid; j < 4 * 8 * 32; j += 256) {
        int n = j >> 8;
        int k = (j >> 5) & 7;
        int d4 = (j & 31) * 4;
        float4 v = *(const float4*)(mem + (size_t)idx_s[k] * HID + (size_t)(n0 + n) * 128 + d4);
        *(float4*)&kv_s[n][k][d4] = v;
    }
    for (int j = tid; j < 4 * 32; j += 256) {
        int n = j >> 5;
        int d4 = (j & 31) * 4;
        *(float4*)&qin_s[n][d4] = *(const float4*)(q + (size_t)(b * NN + n0 + n) * 128 + d4);
    }
    __syncthreads();
    {
        int d = tid & 127, half = tid >> 7;
        for (int n2 = 0; n2 < 2; ++n2) {
            int n = half * 2 + n2;
            float a = in_b[d];
            const float* wr = in_w + (size_t)d * 128;
            #pragma unroll
            for (int i = 0; i < 128; i += 4) {
                float4 w4 = *(const float4*)(wr + i);
                a += w4.x * qin_s[n][i] + w4.y * qin_s[n][i + 1] + w4.z * qin_s[n][i + 2] + w4.w * qin_s[n][i + 3];
            }
            qh_s[n][d] = a;
        }
    }
    {
        int d = tid & 127, layer = tid >> 7;
        float ak[16], av[16];
        #pragma unroll
        for (int p = 0; p < 16; ++p) { ak[p] = in_b[128 + d]; av[p] = in_b[256 + d]; }
        const float* wkr = in_w + (size_t)(128 + d) * 128;
        const float* wvr = in_w + (size_t)(256 + d) * 128;
        for (int i = 0; i < 128; i += 4) {
            float4 wk4 = *(const float4*)(wkr + i);
            float4 wv4 = *(const float4*)(wvr + i);
            #pragma unroll
            for (int p = 0; p < 16; ++p) {
                int pg = layer * 16 + p;
                int n = pg >> 3, k = pg & 7;
                float4 x4 = *(const float4*)&kv_s[n][k][i];
                ak[p] += wk4.x * x4.x + wk4.y * x4.y + wk4.z * x4.z + wk4.w * x4.w;
                av[p] += wv4.x * x4.x + wv4.y * x4.y + wv4.z * x4.z + wv4.w * x4.w;
            }
        }
        #pragma unroll
        for (int p = 0; p < 16; ++p) {
            int pg = layer * 16 + p;
            int n = pg >> 3, k = pg & 7;
            kh_s[n][k][d] = ak[p];
            vh_s[n][k][d] = av[p];
        }
    }
    __syncthreads();
    {
        int n = tid >> 6, lane = tid & 63;
        int dh = lane & 31, hh = lane >> 5;
        #pragma unroll
        for (int hp = 0; hp < 2; ++hp) {
            int h = hp * 2 + hh;
            int dd0 = h * 32 + dh;
            float qv = qh_s[n][dd0];
            float sc[8];
            #pragma unroll
            for (int k = 0; k < 8; ++k) {
                float p = qv * kh_s[n][k][dd0];
                #pragma unroll
                for (int msk = 16; msk >= 1; msk >>= 1) p += __shfl_xor(p, msk, 32);
                sc[k] = p * 0.17677669529663687f;
            }
            float mx = sc[0];
            #pragma unroll
            for (int k = 1; k < 8; ++k) mx = fmaxf(mx, sc[k]);
            float den = 0.f;
            #pragma unroll
            for (int k = 0; k < 8; ++k) { sc[k] = expf(sc[k] - mx); den += sc[k]; }
            float inv = 1.0f / den;
            float c = 0.f;
            #pragma unroll
            for (int k = 0; k < 8; ++k) c += sc[k] * vh_s[n][k][dd0];
            ctx_s[n][dd0] = c * inv;
        }
    }
    __syncthreads();
    {
        int d = tid & 127, half = tid >> 7;
        for (int n2 = 0; n2 < 2; ++n2) {
            int n = half * 2 + n2;
            float a = ob[d];
            const float* wr = ow + (size_t)d * 128;
            #pragma unroll
            for (int i = 0; i < 128; i += 4) {
                float4 w4 = *(const float4*)(wr + i);
                a += w4.x * ctx_s[n][i] + w4.y * ctx_s[n][i + 1] + w4.z * ctx_s[n][i + 2] + w4.w * ctx_s[n][i + 3];
            }
            o1_s[n][d] = a;
        }
    }
    __syncthreads();
    {
        int d = tid & 127, half = tid >> 7;
        for (int n2 = 0; n2 < 2; ++n2) {
            int n = half * 2 + n2;
            float a = pb[d];
            const float* wr = pw + (size_t)d * 128;
            #pragma unroll
            for (int i = 0; i < 128; i += 4) {
                float4 w4 = *(const float4*)(wr + i);
                a += w4.x * o1_s[n][i] + w4.y * o1_s[n][i + 1] + w4.z * o1_s[n][i + 2] + w4.w * o1_s[n][i + 3];
            }
            out[(size_t)(b * NN + n0 + n) * 128 + d] = a;
        }
    }
}

extern "C" void kernel_launch(void* const* d_in, const int* in_sizes, int n_in,
                              void* d_out, int out_size, void* d_ws, size_t ws_size,
                              hipStream_t stream) {
    const float* x_scalar   = (const float*)d_in[0];
    const int*   season_q   = (const int*)d_in[1];
    const float* year_q     = (const float*)d_in[2];
    const float* dw_w       = (const float*)d_in[3];
    const float* dw_b       = (const float*)d_in[4];
    const float* pw_w       = (const float*)d_in[5];
    const float* pw_b       = (const float*)d_in[6];
    const float* ln_g       = (const float*)d_in[7];
    const float* ln_bb      = (const float*)d_in[8];
    const float* in_proj_w  = (const float*)d_in[9];
    const float* in_proj_b  = (const float*)d_in[10];
    const float* out_proj_w = (const float*)d_in[11];
    const float* out_proj_b = (const float*)d_in[12];
    const float* proj_w     = (const float*)d_in[13];
    const float* proj_b     = (const float*)d_in[14];
    const float* memory_bank= (const float*)d_in[15];
    const int*   mem_season = (const int*)d_in[16];
    const float* mem_year   = (const float*)d_in[17];

    float* out_final = (float*)d_out;
    float* q_out = out_final + (size_t)BB_ * NN * DD;

    float* ws = (float*)d_ws;
    size_t off = 0;
    float* QPRE  = ws + off; off += 1048576;
    float* QNORM = ws + off; off += 16;
    float* NRMP  = ws + off; off += 4 * MM;
    float* SIMP  = ws + off; off += 64 * MM;
    int*   TOPK  = (int*)(ws + off); off += 128;
    short* XH    = (short*)(ws + off); off += 524288;   // 1,048,576 bf16
    short* XL    = (short*)(ws + off); off += 524288;
    short* AH    = (short*)(ws + off); off += 16777216; // 33,554,432 bf16
    short* AL    = (short*)(ws + off); off += 16777216;
    bool use_pre = (ws_size >= off * 4);

    // attention buffers alias the AH region (k2 is done with AH before these run)
    short* WQKV16 = AH;                      // 49,152
    short* WC16   = AH + 49152;              // 16,384
    float* BC     = (float*)(AH + 65536);    // 128 f32 (256 shorts)
    short* QH16   = AH + 66048;              // 1,048,576
    short* KH16   = QH16 + 1048576;          // 8,388,608
    short* VH16   = KH16 + 8388608;          // 8,388,608
    short* CTX16  = VH16 + 8388608;          // 1,048,576

    k1_conv<<<dim3(8, 16), 256, 0, stream>>>(x_scalar, dw_w, dw_b, XH, XL);
    if (use_pre) {
        k0_cvt2<<<16384, 256, 0, stream>>>(pw_w, AH, AL);
        k2_split<true><<<8192, 256, 0, stream>>>(pw_w, AH, AL, pw_b, XH, XL, QPRE);
    } else {
        k2_split<false><<<8192, 256, 0, stream>>>(pw_w, nullptr, nullptr, pw_b, XH, XL, QPRE);
    }
    k3_ln<<<2048, 256, 0, stream>>>(QPRE, ln_g, ln_bb, q_out);
    k3b_qnorm<<<16, 256, 0, stream>>>(q_out, QNORM);
    k4_sim<<<dim3(299, 4), 256, 0, stream>>>(memory_bank, q_out, SIMP, NRMP);
    k5_topk<<<16, 256, 0, stream>>>(SIMP, NRMP, QNORM, season_q, year_q, mem_season, mem_year, TOPK);
    if (use_pre) {
        k6w<<<1, 256, 0, stream>>>(in_proj_w, out_proj_w, out_proj_b, proj_w, proj_b, WQKV16, WC16, BC);
        k6q<<<dim3(4, 16), 256, 0, stream>>>(q_out, WQKV16, in_proj_b, QH16);
        k6kv<<<dim3(32, 16), 256, 0, stream>>>(memory_bank, TOPK, WQKV16, in_proj_b, KH16, VH16);
        k6s<<<dim3(64, 16), 256, 0, stream>>>(QH16, KH16, VH16, CTX16);
        k6f<<<64, 256, 0, stream>>>(CTX16, WC16, BC, out_final);
    } else {
        k6_attn<<<dim3(128, 16), 256, 0, stream>>>(memory_bank, q_out, TOPK, in_proj_w, in_proj_b,
                                                   out_proj_w, out_proj_b, proj_w, proj_b, out_final);
    }
}

// Round 15
// 658.626 us; speedup vs baseline: 1.0810x; 1.0810x over previous
//
#include <hip/hip_runtime.h>
#include <hip/hip_bf16.h>

#define BB_ 16
#define TT_ 96
#define NN 512
#define DD 128
#define MM 1196
#define KK 8
#define HID 65536
#define TP 97
#define TPAD 128

typedef __attribute__((ext_vector_type(8))) short short8v;
typedef __attribute__((ext_vector_type(4))) float f32x4;

__device__ __forceinline__ float gelu_exact(float x) {
    return 0.5f * x * (1.0f + erff(x * 0.70710678118654752f));
}
__device__ __forceinline__ unsigned rne16(float f) {
    unsigned u = __float_as_uint(f);
    return (u + 0x7fffu + ((u >> 16) & 1u)) >> 16;
}
__device__ __forceinline__ float bf2f(short s) {
    return __uint_as_float(((unsigned)(unsigned short)s) << 16);
}
// split f32 -> bf16 hi + bf16 lo (hi = rne(x), lo = rne(x - hi))
__device__ __forceinline__ void split2(float x, short& hi, short& lo) {
    unsigned h = rne16(x);
    hi = (short)h;
    float hf = __uint_as_float(h << 16);
    lo = (short)rne16(x - hf);
}
__device__ __forceinline__ void gload_lds16(const void* g, void* l) {
    __builtin_amdgcn_global_load_lds((const __attribute__((address_space(1))) void*)g,
                                     (__attribute__((address_space(3))) void*)l, 16, 0, 0);
}
__device__ __forceinline__ short8v pack8(float4 a, float4 b) {
    short t[8];
    t[0] = (short)rne16(a.x); t[1] = (short)rne16(a.y);
    t[2] = (short)rne16(a.z); t[3] = (short)rne16(a.w);
    t[4] = (short)rne16(b.x); t[5] = (short)rne16(b.y);
    t[6] = (short)rne16(b.z); t[7] = (short)rne16(b.w);
    return *(short8v*)t;
}
// k2 swizzle for 32-elem (4-chunk) rows: period-16 bank-complete (r7-proven)
__device__ __forceinline__ int swz32(int row) {
    return (row & 3) ^ ((row >> 2) & 3);
}
// stage a 128x128 bf16 tile (row-major, 128-short rows) from global into XOR-swizzled LDS
__device__ __forceinline__ void stage_tile_sw(const short* g, short* lds, int tid) {
    #pragma unroll
    for (int j = 0; j < 8; ++j) {
        int row = j * 16 + (tid >> 4);
        int csrc = (tid & 15) ^ (row & 7);
        gload_lds16(g + row * 128 + csrc * 8, lds + j * 2048 + tid * 8);
    }
}
// fragment read from swizzled 128x128 tile: row, k-iter kk (0..3), lk (0..3)
__device__ __forceinline__ short8v frag_ld(const short* lds, int row, int kk, int lk) {
    return *(const short8v*)&lds[row * 128 + (((kk << 2) + lk) ^ (row & 7)) * 8];
}

// K0: pw_w f32 -> (hi, lo) bf16 pair
__global__ __launch_bounds__(256) void k0_cvt2(const float* __restrict__ src,
                                               short* __restrict__ hi, short* __restrict__ lo) {
    size_t i = ((size_t)blockIdx.x * 256 + threadIdx.x) * 8;
    float4 a = *(const float4*)(src + i);
    float4 b = *(const float4*)(src + i + 4);
    short h[8], l[8];
    split2(a.x, h[0], l[0]); split2(a.y, h[1], l[1]);
    split2(a.z, h[2], l[2]); split2(a.w, h[3], l[3]);
    split2(b.x, h[4], l[4]); split2(b.y, h[5], l[5]);
    split2(b.z, h[6], l[6]); split2(b.w, h[7], l[7]);
    *(short8v*)(hi + i) = *(short8v*)h;
    *(short8v*)(lo + i) = *(short8v*)l;
}

// K1: depthwise conv + bias + exact gelu -> xct hi/lo bf16, layout [b][t][n], zero-padded t>=97
__global__ __launch_bounds__(256) void k1_conv(const float* __restrict__ x,
                                               const float* __restrict__ dw_w,
                                               const float* __restrict__ dw_b,
                                               short* __restrict__ xh,
                                               short* __restrict__ xl) {
    int b = blockIdx.y, n0 = blockIdx.x * 64;
    __shared__ float xs[96][64];
    __shared__ float ws[64][12];
    __shared__ float bs[64];
    int tid = threadIdx.x;
    for (int j = tid; j < 96 * 64; j += 256) {
        int t = j / 64, n = j % 64;
        xs[t][n] = x[(size_t)(b * TT_ + t) * NN + n0 + n];
    }
    for (int j = tid; j < 64 * 12; j += 256) {
        int n = j / 12, k = j % 12;
        ws[n][k] = dw_w[(size_t)(n0 + n) * 12 + k];
    }
    if (tid < 64) bs[tid] = dw_b[n0 + tid];
    __syncthreads();
    int n = tid % 64, g = tid / 64;
    for (int t = g; t < TP; t += 4) {
        float acc = bs[n];
        #pragma unroll
        for (int k = 0; k < 12; ++k) {
            int ti = t - 6 + k;
            if (ti >= 0 && ti < 96) acc += xs[ti][n] * ws[n][k];
        }
        float v = gelu_exact(acc);
        short h, l;
        split2(v, h, l);
        size_t idx = ((size_t)b * TPAD + t) * NN + n0 + n;
        xh[idx] = h; xl[idx] = l;
    }
    for (int t = TP + g; t < TPAD; t += 4) {
        size_t idx = ((size_t)b * TPAD + t) * NN + n0 + n;
        xh[idx] = 0; xl[idx] = 0;
    }
}

// K2: split-bf16 3-pass MFMA GEMM, BK=32, 32 KB LDS -> 4 blocks/CU (r13 config, 340 us;
// (256,5) attempt in r14 forced VGPR 60->48 and spilled -> reverted).
// 1x4 wave layout: wave w owns o-strip [w*32, w*32+32) x ALL t. t-frag 7 (t=112..127,
// identically zero) dropped with COMPILE-TIME bounds (n<7). Epilogue: per-wave rows,
// float4 direct store. XCD-aware 1-D grid: xcd owns o-groups [xcd*64, xcd*64+64).
template <bool PRE>
__global__ __launch_bounds__(256, 4) void k2_split(const float* __restrict__ pw_w,
                                                   const short* __restrict__ aH,
                                                   const short* __restrict__ aL,
                                                   const float* __restrict__ pw_b,
                                                   const short* __restrict__ bH,
                                                   const short* __restrict__ bL,
                                                   float* __restrict__ q_pre) {
    int wgid = blockIdx.x;
    int xcd = wgid & 7;
    int r = wgid >> 3;
    int b = r & 15;
    int o0 = (xcd * 64 + (r >> 4)) * 128;
    __shared__ short AsH[4096], AsL[4096], BsH[4096], BsL[4096];
    int tid = threadIdx.x;
    int l = tid & 63, w = tid >> 6;
    int lrow = l & 15, lk = l >> 4;
    const short* bHb = bH + (size_t)b * TPAD * NN;
    const short* bLb = bL + (size_t)b * TPAD * NN;

    f32x4 acc[2][7];
    #pragma unroll
    for (int m = 0; m < 2; ++m)
        #pragma unroll
        for (int n = 0; n < 7; ++n) acc[m][n] = (f32x4){0.f, 0.f, 0.f, 0.f};

    for (int it = 0; it < 16; ++it) {
        int k0 = it * 32;
        #pragma unroll
        for (int j = 0; j < 2; ++j) {
            int row = j * 64 + (tid >> 2);
            int c = tid & 3;
            int sc = c ^ swz32(row);           // pre-swizzled source chunk
            int dofs = (j * 256 + tid) * 8;    // linear LDS dest
            // B rows 112..127 are never read (zero t-frag dropped) -> skip staging
            if (!(j == 1 && (tid >> 2) >= 48)) {
                gload_lds16(bHb + (size_t)row * NN + k0 + sc * 8, &BsH[dofs]);
                gload_lds16(bLb + (size_t)row * NN + k0 + sc * 8, &BsL[dofs]);
            }
            if constexpr (PRE) {
                gload_lds16(aH + (size_t)(o0 + row) * 512 + k0 + sc * 8, &AsH[dofs]);
                gload_lds16(aL + (size_t)(o0 + row) * 512 + k0 + sc * 8, &AsL[dofs]);
            } else {
                const float* src = pw_w + (size_t)(o0 + row) * 512 + k0 + c * 8;
                float4 v0 = *(const float4*)(src);
                float4 v1 = *(const float4*)(src + 4);
                short h[8], lo[8];
                split2(v0.x, h[0], lo[0]); split2(v0.y, h[1], lo[1]);
                split2(v0.z, h[2], lo[2]); split2(v0.w, h[3], lo[3]);
                split2(v1.x, h[4], lo[4]); split2(v1.y, h[5], lo[5]);
                split2(v1.z, h[6], lo[6]); split2(v1.w, h[7], lo[7]);
                int didx = row * 32 + (c ^ swz32(row)) * 8;
                *(short8v*)&AsH[didx] = *(short8v*)h;
                *(short8v*)&AsL[didx] = *(short8v*)lo;
            }
        }
        __syncthreads();
        short8v ah[2], al[2];
        #pragma unroll
        for (int m = 0; m < 2; ++m) {
            int row = w * 32 + m * 16 + lrow;
            int idx = row * 32 + (lk ^ swz32(row)) * 8;
            ah[m] = *(const short8v*)&AsH[idx];
            al[m] = *(const short8v*)&AsL[idx];
        }
        #pragma unroll
        for (int n = 0; n < 7; ++n) {
            int row = n * 16 + lrow;
            int idx = row * 32 + (lk ^ swz32(row)) * 8;
            short8v bh = *(const short8v*)&BsH[idx];
            short8v bl = *(const short8v*)&BsL[idx];
            #pragma unroll
            for (int m = 0; m < 2; ++m) {
                acc[m][n] = __builtin_amdgcn_mfma_f32_16x16x32_bf16(ah[m], bh, acc[m][n], 0, 0, 0);
                acc[m][n] = __builtin_amdgcn_mfma_f32_16x16x32_bf16(ah[m], bl, acc[m][n], 0, 0, 0);
                acc[m][n] = __builtin_amdgcn_mfma_f32_16x16x32_bf16(al[m], bh, acc[m][n], 0, 0, 0);
            }
        }
        __syncthreads();
    }
    // epilogue: bias + exact gelu + mask t<97 + mean over t; per-wave rows, direct store
    #pragma unroll
    for (int m = 0; m < 2; ++m) {
        float s4[4];
        #pragma unroll
        for (int reg = 0; reg < 4; ++reg) {
            int o_loc = w * 32 + m * 16 + lk * 4 + reg;
            float bias = pw_b[o0 + o_loc];
            float s = 0.f;
            #pragma unroll
            for (int n = 0; n < 7; ++n) {
                int t = n * 16 + lrow;
                if (t < TP) s += gelu_exact(acc[m][n][reg] + bias);
            }
            s += __shfl_xor(s, 1, 64);
            s += __shfl_xor(s, 2, 64);
            s += __shfl_xor(s, 4, 64);
            s += __shfl_xor(s, 8, 64);
            s4[reg] = s * (1.0f / 97.0f);
        }
        if (lrow == 0) {
            int o_loc = w * 32 + m * 16 + lk * 4;
            *(float4*)(q_pre + (size_t)b * HID + o0 + o_loc) = make_float4(s4[0], s4[1], s4[2], s4[3]);
        }
    }
}

// K3: LayerNorm over D=128 per row; writes q (second output)
__global__ __launch_bounds__(256) void k3_ln(const float* __restrict__ q_pre,
                                             const float* __restrict__ g,
                                             const float* __restrict__ beta,
                                             float* __restrict__ qout) {
    int row = blockIdx.x * 4 + (threadIdx.x >> 6);
    int lane = threadIdx.x & 63;
    const float* src = q_pre + (size_t)row * 128;
    float v0 = src[lane], v1 = src[lane + 64];
    float s = v0 + v1;
    #pragma unroll
    for (int m = 32; m >= 1; m >>= 1) s += __shfl_xor(s, m, 64);
    float mu = s * (1.f / 128.f);
    float d0 = v0 - mu, d1 = v1 - mu;
    float vs = d0 * d0 + d1 * d1;
    #pragma unroll
    for (int m = 32; m >= 1; m >>= 1) vs += __shfl_xor(vs, m, 64);
    float rstd = rsqrtf(vs * (1.f / 128.f) + 1e-5f);
    qout[(size_t)row * 128 + lane] = d0 * rstd * g[lane] + beta[lane];
    qout[(size_t)row * 128 + lane + 64] = d1 * rstd * g[lane + 64] + beta[lane + 64];
}

// K3b: per-b L2 norm of q
__global__ __launch_bounds__(256) void k3b_qnorm(const float* __restrict__ q, float* __restrict__ qnorm) {
    int b = blockIdx.x;
    const float* src = q + (size_t)b * HID;
    float s = 0.f;
    for (int i = threadIdx.x * 4; i < HID; i += 256 * 4) {
        float4 v = *(const float4*)(src + i);
        s += v.x * v.x + v.y * v.y + v.z * v.z + v.w * v.w;
    }
    #pragma unroll
    for (int m = 32; m >= 1; m >>= 1) s += __shfl_xor(s, m, 64);
    __shared__ float red[4];
    if ((threadIdx.x & 63) == 0) red[threadIdx.x >> 6] = s;
    __syncthreads();
    if (threadIdx.x == 0) qnorm[b] = sqrtf(red[0] + red[1] + red[2] + red[3]);
}

// K4: fused (mem row sumsq) + (16 q-dots), m-tile=4, deterministic K-split partials
__global__ __launch_bounds__(256) void k4_sim(const float* __restrict__ mem,
                                              const float* __restrict__ q,
                                              float* __restrict__ sim_part,
                                              float* __restrict__ nrm_part) {
    int m0 = blockIdx.x * 4;
    int isp = blockIdx.y;
    int tid = threadIdx.x;
    float acc[4][16];
    float nr[4] = {0.f, 0.f, 0.f, 0.f};
    #pragma unroll
    for (int a = 0; a < 4; ++a)
        #pragma unroll
        for (int c = 0; c < 16; ++c) acc[a][c] = 0.f;
    int ibase = isp * 16384;
    for (int it = 0; it < 16; ++it) {
        int i = ibase + (it * 256 + tid) * 4;
        float4 mv[4];
        #pragma unroll
        for (int a = 0; a < 4; ++a) {
            mv[a] = *(const float4*)(mem + (size_t)(m0 + a) * HID + i);
            nr[a] += mv[a].x * mv[a].x + mv[a].y * mv[a].y + mv[a].z * mv[a].z + mv[a].w * mv[a].w;
        }
        #pragma unroll
        for (int c = 0; c < 16; ++c) {
            float4 qv = *(const float4*)(q + (size_t)c * HID + i);
            #pragma unroll
            for (int a = 0; a < 4; ++a)
                acc[a][c] += mv[a].x * qv.x + mv[a].y * qv.y + mv[a].z * qv.z + mv[a].w * qv.w;
        }
    }
    __shared__ float red[4][68];
    int wv = tid >> 6, lane = tid & 63;
    #pragma unroll
    for (int a = 0; a < 4; ++a)
        for (int c = 0; c < 17; ++c) {
            float v = (c < 16) ? acc[a][c] : nr[a];
            #pragma unroll
            for (int m = 32; m >= 1; m >>= 1) v += __shfl_xor(v, m, 64);
            if (lane == 0) red[wv][a * 17 + c] = v;
        }
    __syncthreads();
    if (tid < 68) {
        float v = red[0][tid] + red[1][tid] + red[2][tid] + red[3][tid];
        int a = tid / 17, r = tid % 17;
        if (r < 16) sim_part[((size_t)isp * 16 + r) * MM + m0 + a] = v;
        else nrm_part[(size_t)isp * MM + m0 + a] = v;
    }
}

// K5: combine, normalize, mask, diversity, top-8 (tie -> lower index)
__global__ __launch_bounds__(256) void k5_topk(const float* __restrict__ sim_part,
                                               const float* __restrict__ nrm_part,
                                               const float* __restrict__ qnorm,
                                               const int* __restrict__ season_q,
                                               const float* __restrict__ year_q,
                                               const int* __restrict__ mem_season,
                                               const float* __restrict__ mem_year,
                                               int* __restrict__ topk) {
    int b = blockIdx.x;
    int tid = threadIdx.x;
    __shared__ float sadj[MM];
    float nq = fmaxf(qnorm[b], 1e-12f);
    int sq = season_q[b];
    float yq = year_q[b];
    for (int m = tid; m < MM; m += 256) {
        float dot = 0.f, ns = 0.f;
        #pragma unroll
        for (int p = 0; p < 4; ++p) {
            dot += sim_part[((size_t)p * 16 + b) * MM + m];
            ns += nrm_part[(size_t)p * MM + m];
        }
        float nm = fmaxf(sqrtf(ns), 1e-12f);
        float s = dot / (nq * nm);
        if (mem_season[m] != sq) s = -10000.0f;
        float dy = fabsf(yq - mem_year[m]);
        float dv = 1.0f - expf(-dy * 0.5f);
        s *= (0.5f + 0.5f * dv);
        sadj[m] = s;
    }
    __syncthreads();
    __shared__ float rv[4];
    __shared__ int ri[4];
    for (int it = 0; it < 8; ++it) {
        float bv = -INFINITY;
        int bi = -1;
        for (int m = tid; m < MM; m += 256) {
            float v = sadj[m];
            if (v > bv || (v == bv && bi >= 0 && m < bi)) { bv = v; bi = m; }
        }
        #pragma unroll
        for (int msk = 32; msk >= 1; msk >>= 1) {
            float ov = __shfl_xor(bv, msk, 64);
            int oi = __shfl_xor(bi, msk, 64);
            if (oi >= 0 && (ov > bv || (ov == bv && (bi < 0 || oi < bi)))) { bv = ov; bi = oi; }
        }
        int lane = tid & 63, wv = tid >> 6;
        if (lane == 0) { rv[wv] = bv; ri[wv] = bi; }
        __syncthreads();
        if (tid == 0) {
            float fv = rv[0]; int fi = ri[0];
            for (int w = 1; w < 4; ++w)
                if (ri[w] >= 0 && (rv[w] > fv || (rv[w] == fv && (fi < 0 || ri[w] < fi)))) { fv = rv[w]; fi = ri[w]; }
            topk[b * KK + it] = fi;
            sadj[fi] = -INFINITY;
        }
        __syncthreads();
    }
}

// K6w: weight prep — bf16 Wq/Wk/Wv; combined Wc = proj_w@out_proj_w (bf16), bc = proj_w@out_proj_b + proj_b
__global__ __launch_bounds__(256) void k6w(const float* __restrict__ in_w,
                                           const float* __restrict__ ow,
                                           const float* __restrict__ ob,
                                           const float* __restrict__ pw,
                                           const float* __restrict__ pb,
                                           short* __restrict__ WQKV16,
                                           short* __restrict__ WC16,
                                           float* __restrict__ BC) {
    __shared__ float ow_s[16384];
    int tid = threadIdx.x;
    for (int i = tid * 4; i < 16384; i += 1024)
        *(float4*)&ow_s[i] = *(const float4*)&ow[i];
    for (int i = tid * 8; i < 49152; i += 2048) {
        float4 a = *(const float4*)(in_w + i);
        float4 b = *(const float4*)(in_w + i + 4);
        *(short8v*)(WQKV16 + i) = pack8(a, b);
    }
    __syncthreads();
    int d = tid >> 1, j0 = (tid & 1) * 64;
    float accv[64];
    #pragma unroll
    for (int j = 0; j < 64; ++j) accv[j] = 0.f;
    for (int i = 0; i < 128; ++i) {
        float wv = pw[d * 128 + i];
        const float* orow = &ow_s[i * 128 + j0];
        #pragma unroll
        for (int j = 0; j < 64; ++j) accv[j] += wv * orow[j];
    }
    #pragma unroll
    for (int j = 0; j < 64; ++j) WC16[d * 128 + j0 + j] = (short)rne16(accv[j]);
    if (tid < 128) {
        float s = pb[tid];
        for (int i = 0; i < 128; ++i) s += pw[tid * 128 + i] * ob[i];
        BC[tid] = s;
    }
}

// K6q: QH = q @ Wq^T + bq  (per b, 128-row tiles), bf16 out
__global__ __launch_bounds__(256) void k6q(const float* __restrict__ q,
                                           const short* __restrict__ WQKV16,
                                           const float* __restrict__ in_b,
                                           short* __restrict__ QH16) {
    int b = blockIdx.y;
    int n0 = blockIdx.x * 128;
    __shared__ short As[16384], Ws[16384];
    int tid = threadIdx.x;
    int l = tid & 63, w = tid >> 6;
    int wr = w >> 1, wc = w & 1;
    int lrow = l & 15, lk = l >> 4;

    stage_tile_sw(WQKV16, Ws, tid);
    {
        int row = tid >> 1, half = tid & 1;
        const float* src = q + ((size_t)b * NN + n0 + row) * 128 + half * 64;
        #pragma unroll
        for (int cc = 0; cc < 8; ++cc) {
            float4 v0 = *(const float4*)(src + cc * 8);
            float4 v1 = *(const float4*)(src + cc * 8 + 4);
            int chunk = half * 8 + cc;
            *(short8v*)&As[row * 128 + (chunk ^ (row & 7)) * 8] = pack8(v0, v1);
        }
    }
    __syncthreads();
    f32x4 acc[4][4];
    #pragma unroll
    for (int m = 0; m < 4; ++m)
        #pragma unroll
        for (int n = 0; n < 4; ++n) acc[m][n] = (f32x4){0.f, 0.f, 0.f, 0.f};
    #pragma unroll
    for (int kk = 0; kk < 4; ++kk) {
        short8v a[4], bw[4];
        #pragma unroll
        for (int m = 0; m < 4; ++m) a[m] = frag_ld(As, wr * 64 + m * 16 + lrow, kk, lk);
        #pragma unroll
        for (int n = 0; n < 4; ++n) bw[n] = frag_ld(Ws, wc * 64 + n * 16 + lrow, kk, lk);
        #pragma unroll
        for (int m = 0; m < 4; ++m)
            #pragma unroll
            for (int n = 0; n < 4; ++n)
                acc[m][n] = __builtin_amdgcn_mfma_f32_16x16x32_bf16(a[m], bw[n], acc[m][n], 0, 0, 0);
    }
    #pragma unroll
    for (int m = 0; m < 4; ++m)
        #pragma unroll
        for (int n = 0; n < 4; ++n)
            #pragma unroll
            for (int reg = 0; reg < 4; ++reg) {
                int r = wr * 64 + m * 16 + lk * 4 + reg;
                int dco = wc * 64 + n * 16 + lrow;
                QH16[((size_t)b * NN + n0 + r) * 128 + dco] = (short)rne16(acc[m][n][reg] + in_b[dco]);
            }
}

// K6kv: gather kv rows, project with Wk and Wv (shared A-tile), bf16 out
__global__ __launch_bounds__(256) void k6kv(const float* __restrict__ mem,
                                            const int* __restrict__ topk,
                                            const short* __restrict__ WQKV16,
                                            const float* __restrict__ in_b,
                                            short* __restrict__ KH16,
                                            short* __restrict__ VH16) {
    int b = blockIdx.y;
    int n0 = blockIdx.x * 16;
    __shared__ short As[16384], WkS[16384], WvS[16384];
    __shared__ int idx_s[8];
    int tid = threadIdx.x;
    int l = tid & 63, w = tid >> 6;
    int wr = w >> 1, wc = w & 1;
    int lrow = l & 15, lk = l >> 4;
    if (tid < 8) idx_s[tid] = topk[b * 8 + tid];
    stage_tile_sw(WQKV16 + 16384, WkS, tid);
    stage_tile_sw(WQKV16 + 32768, WvS, tid);
    __syncthreads();
    {
        int row = tid >> 1, half = tid & 1;
        int n = n0 + (row >> 3), k = row & 7;
        const float* src = mem + (size_t)idx_s[k] * HID + (size_t)n * 128 + half * 64;
        #pragma unroll
        for (int cc = 0; cc < 8; ++cc) {
            float4 v0 = *(const float4*)(src + cc * 8);
            float4 v1 = *(const float4*)(src + cc * 8 + 4);
            int chunk = half * 8 + cc;
            *(short8v*)&As[row * 128 + (chunk ^ (row & 7)) * 8] = pack8(v0, v1);
        }
    }
    __syncthreads();
    f32x4 ak_[4][4], av_[4][4];
    #pragma unroll
    for (int m = 0; m < 4; ++m)
        #pragma unroll
        for (int n = 0; n < 4; ++n) {
            ak_[m][n] = (f32x4){0.f, 0.f, 0.f, 0.f};
            av_[m][n] = (f32x4){0.f, 0.f, 0.f, 0.f};
        }
    #pragma unroll
    for (int kk = 0; kk < 4; ++kk) {
        short8v a[4], bk[4], bv[4];
        #pragma unroll
        for (int m = 0; m < 4; ++m) a[m] = frag_ld(As, wr * 64 + m * 16 + lrow, kk, lk);
        #pragma unroll
        for (int n = 0; n < 4; ++n) {
            bk[n] = frag_ld(WkS, wc * 64 + n * 16 + lrow, kk, lk);
            bv[n] = frag_ld(WvS, wc * 64 + n * 16 + lrow, kk, lk);
        }
        #pragma unroll
        for (int m = 0; m < 4; ++m)
            #pragma unroll
            for (int n = 0; n < 4; ++n) {
                ak_[m][n] = __builtin_amdgcn_mfma_f32_16x16x32_bf16(a[m], bk[n], ak_[m][n], 0, 0, 0);
                av_[m][n] = __builtin_amdgcn_mfma_f32_16x16x32_bf16(a[m], bv[n], av_[m][n], 0, 0, 0);
            }
    }
    #pragma unroll
    for (int m = 0; m < 4; ++m)
        #pragma unroll
        for (int n = 0; n < 4; ++n)
            #pragma unroll
            for (int reg = 0; reg < 4; ++reg) {
                int r = wr * 64 + m * 16 + lk * 4 + reg;
                int dco = wc * 64 + n * 16 + lrow;
                int nl = r >> 3, k = r & 7;
                size_t o = (((size_t)b * NN + n0 + nl) * 8 + k) * 128 + dco;
                KH16[o] = (short)rne16(ak_[m][n][reg] + in_b[128 + dco]);
                VH16[o] = (short)rne16(av_[m][n][reg] + in_b[256 + dco]);
            }
}

// K6s: scores + softmax + ctx. Vectorized: each lane owns 4 consecutive d (short4 = 8B loads);
// head = octet (8 lanes x 4 d = 32 d); reduction = 3-step octet butterfly.
__global__ __launch_bounds__(256) void k6s(const short* __restrict__ QH16,
                                           const short* __restrict__ KH16,
                                           const short* __restrict__ VH16,
                                           short* __restrict__ CTX16) {
    int b = blockIdx.y;
    int n = blockIdx.x * 8 + (threadIdx.x >> 5);
    int dh = threadIdx.x & 31;
    int d0 = dh * 4;
    size_t qbase = ((size_t)b * NN + n) * 128;
    size_t kvbase = qbase * 8;
    short4 q4 = *(const short4*)(QH16 + qbase + d0);
    float q0 = bf2f(q4.x), q1 = bf2f(q4.y), q2 = bf2f(q4.z), q3 = bf2f(q4.w);
    float sc[8];
    #pragma unroll
    for (int k = 0; k < 8; ++k) {
        short4 k4 = *(const short4*)(KH16 + kvbase + k * 128 + d0);
        float p = q0 * bf2f(k4.x) + q1 * bf2f(k4.y) + q2 * bf2f(k4.z) + q3 * bf2f(k4.w);
        p += __shfl_xor(p, 1, 32);
        p += __shfl_xor(p, 2, 32);
        p += __shfl_xor(p, 4, 32);
        sc[k] = p * 0.17677669529663687f;
    }
    float mx = sc[0];
    #pragma unroll
    for (int k = 1; k < 8; ++k) mx = fmaxf(mx, sc[k]);
    float den = 0.f;
    #pragma unroll
    for (int k = 0; k < 8; ++k) { sc[k] = expf(sc[k] - mx); den += sc[k]; }
    float inv = 1.0f / den;
    float c0 = 0.f, c1 = 0.f, c2 = 0.f, c3 = 0.f;
    #pragma unroll
    for (int k = 0; k < 8; ++k) {
        short4 v4 = *(const short4*)(VH16 + kvbase + k * 128 + d0);
        c0 += sc[k] * bf2f(v4.x);
        c1 += sc[k] * bf2f(v4.y);
        c2 += sc[k] * bf2f(v4.z);
        c3 += sc[k] * bf2f(v4.w);
    }
    short4 o4;
    o4.x = (short)rne16(c0 * inv);
    o4.y = (short)rne16(c1 * inv);
    o4.z = (short)rne16(c2 * inv);
    o4.w = (short)rne16(c3 * inv);
    *(short4*)(CTX16 + qbase + d0) = o4;
}

// K6f: out = ctx @ Wc^T + bc (128-row tiles over all 8192 rows), f32 out
__global__ __launch_bounds__(256) void k6f(const short* __restrict__ CTX16,
                                           const short* __restrict__ WC16,
                                           const float* __restrict__ BC,
                                           float* __restrict__ out) {
    int r0 = blockIdx.x * 128;
    __shared__ short As[16384], Ws[16384];
    int tid = threadIdx.x;
    int l = tid & 63, w = tid >> 6;
    int wr = w >> 1, wc = w & 1;
    int lrow = l & 15, lk = l >> 4;
    stage_tile_sw(CTX16 + (size_t)r0 * 128, As, tid);
    stage_tile_sw(WC16, Ws, tid);
    __syncthreads();
    f32x4 acc[4][4];
    #pragma unroll
    for (int m = 0; m < 4; ++m)
        #pragma unroll
        for (int n = 0; n < 4; ++n) acc[m][n] = (f32x4){0.f, 0.f, 0.f, 0.f};
    #pragma unroll
    for (int kk = 0; kk < 4; ++kk) {
        short8v a[4], bw[4];
        #pragma unroll
        for (int m = 0; m < 4; ++m) a[m] = frag_ld(As, wr * 64 + m * 16 + lrow, kk, lk);
        #pragma unroll
        for (int n = 0; n < 4; ++n) bw[n] = frag_ld(Ws, wc * 64 + n * 16 + lrow, kk, lk);
        #pragma unroll
        for (int m = 0; m < 4; ++m)
            #pragma unroll
            for (int n = 0; n < 4; ++n)
                acc[m][n] = __builtin_amdgcn_mfma_f32_16x16x32_bf16(a[m], bw[n], acc[m][n], 0, 0, 0);
    }
    #pragma unroll
    for (int m = 0; m < 4; ++m)
        #pragma unroll
        for (int n = 0; n < 4; ++n)
            #pragma unroll
            for (int reg = 0; reg < 4; ++reg) {
                int r = wr * 64 + m * 16 + lk * 4 + reg;
                int dco = wc * 64 + n * 16 + lrow;
                out[(size_t)(r0 + r) * 128 + dco] = acc[m][n][reg] + BC[dco];
            }
}

// K6 fallback monolith (used only if ws too small for the split attention path)
__global__ __launch_bounds__(256) void k6_attn(const float* __restrict__ mem,
                                               const float* __restrict__ q,
                                               const int* __restrict__ topk,
                                               const float* __restrict__ in_w,
                                               const float* __restrict__ in_b,
                                               const float* __restrict__ ow,
                                               const float* __restrict__ ob,
                                               const float* __restrict__ pw,
                                               const float* __restrict__ pb,
                                               float* __restrict__ out) {
    int b = blockIdx.y;
    int n0 = blockIdx.x * 4;
    int tid = threadIdx.x;
    __shared__ float kv_s[4][8][128];
    __shared__ float kh_s[4][8][128];
    __shared__ float vh_s[4][8][128];
    __shared__ float qin_s[4][128];
    __shared__ float qh_s[4][128];
    __shared__ float ctx_s[4][128];
    __shared__ float o1_s[4][128];
    __shared__ int idx_s[8];
    if (tid < 8) idx_s[tid] = topk[b * 8 + tid];
    __syncthreads();
    for (int j = tid; j < 4 * 8 * 32; j += 256) {
        int n = j >> 8;
        int k = (j >> 5) & 7;
        int d4 = (j & 31) * 4;
        float4 v = *(const float4*)(mem + (size_t)idx_s[k] * HID + (size_t)(n0 + n) * 128 + d4);
        *(float4*)&kv_s[n][k][d4] = v;
    }
    for (int j = tid; j < 4 * 32; j += 256) {
        int n = j >> 5;
        int d4 = (j & 31) * 4;
        *(float4*)&qin_s[n][d4] = *(const float4*)(q + (size_t)(b * NN + n0 + n) * 128 + d4);
    }
    __syncthreads();
    {
        int d = tid & 127, half = tid >> 7;
        for (int n2 = 0; n2 < 2; ++n2) {
            int n = half * 2 + n2;
            float a = in_b[d];
            const float* wr = in_w + (size_t)d * 128;
            #pragma unroll
            for (int i = 0; i < 128; i += 4) {
                float4 w4 = *(const float4*)(wr + i);
                a += w4.x * qin_s[n][i] + w4.y * qin_s[n][i + 1] + w4.z * qin_s[n][i + 2] + w4.w * qin_s[n][i + 3];
            }
            qh_s[n][d] = a;
        }
    }
    {
        int d = tid & 127, layer = tid >> 7;
        float ak[16], av[16];
        #pragma unroll
        for (int p = 0; p < 16; ++p) { ak[p] = in_b[128 + d]; av[p] = in_b[256 + d]; }
        const float* wkr = in_w + (size_t)(128 + d) * 128;
        const float* wvr = in_w + (size_t)(256 + d) * 128;
        for (int i = 0; i < 128; i += 4) {
            float4 wk4 = *(const float4*)(wkr + i);
            float4 wv4 = *(const float4*)(wvr + i);
            #pragma unroll
            for (int p = 0; p < 16; ++p) {
                int pg = layer * 16 + p;
                int n = pg >> 3, k = pg & 7;
                float4 x4 = *(const float4*)&kv_s[n][k][i];
                ak[p] += wk4.x * x4.x + wk4.y * x4.y + wk4.z * x4.z + wk4.w * x4.w;
                av[p] += wv4.x * x4.x + wv4.y * x4.y + wv4.z * x4.z + wv4.w * x4.w;
            }
        }
        #pragma unroll
        for (int p = 0; p < 16; ++p) {
            int pg = layer * 16 + p;
            int n = pg >> 3, k = pg & 7;
            kh_s[n][k][d] = ak[p];
            vh_s[n][k][d] = av[p];
        }
    }
    __syncthreads();
    {
        int n = tid >> 6, lane = tid & 63;
        int dh = lane & 31, hh = lane >> 5;
        #pragma unroll
        for (int hp = 0; hp < 2; ++hp) {
            int h = hp * 2 + hh;
            int dd0 = h * 32 + dh;
            float qv = qh_s[n][dd0];
            float sc[8];
            #pragma unroll
            for (int k = 0; k < 8; ++k) {
                float p = qv * kh_s[n][k][dd0];
                #pragma unroll
                for (int msk = 16; msk >= 1; msk >>= 1) p += __shfl_xor(p, msk, 32);
                sc[k] = p * 0.17677669529663687f;
            }
            float mx = sc[0];
            #pragma unroll
            for (int k = 1; k < 8; ++k) mx = fmaxf(mx, sc[k]);
            float den = 0.f;
            #pragma unroll
            for (int k = 0; k < 8; ++k) { sc[k] = expf(sc[k] - mx); den += sc[k]; }
            float inv = 1.0f / den;
            float c = 0.f;
            #pragma unroll
            for (int k = 0; k < 8; ++k) c += sc[k] * vh_s[n][k][dd0];
            ctx_s[n][dd0] = c * inv;
        }
    }
    __syncthreads();
    {
        int d = tid & 127, half = tid >> 7;
        for (int n2 = 0; n2 < 2; ++n2) {
            int n = half * 2 + n2;
            float a = ob[d];
            const float* wr = ow + (size_t)d * 128;
            #pragma unroll
            for (int i = 0; i < 128; i += 4) {
                float4 w4 = *(const float4*)(wr + i);
                a += w4.x * ctx_s[n][i] + w4.y * ctx_s[n][i + 1] + w4.z * ctx_s[n][i + 2] + w4.w * ctx_s[n][i + 3];
            }
            o1_s[n][d] = a;
        }
    }
    __syncthreads();
    {
        int d = tid & 127, half = tid >> 7;
        for (int n2 = 0; n2 < 2; ++n2) {
            int n = half * 2 + n2;
            float a = pb[d];
            const float* wr = pw + (size_t)d * 128;
            #pragma unroll
            for (int i = 0; i < 128; i += 4) {
                float4 w4 = *(const float4*)(wr + i);
                a += w4.x * o1_s[n][i] + w4.y * o1_s[n][i + 1] + w4.z * o1_s[n][i + 2] + w4.w * o1_s[n][i + 3];
            }
            out[(size_t)(b * NN + n0 + n) * 128 + d] = a;
        }
    }
}

extern "C" void kernel_launch(void* const* d_in, const int* in_sizes, int n_in,
                              void* d_out, int out_size, void* d_ws, size_t ws_size,
                              hipStream_t stream) {
    const float* x_scalar   = (const float*)d_in[0];
    const int*   season_q   = (const int*)d_in[1];
    const float* year_q     = (const float*)d_in[2];
    const float* dw_w       = (const float*)d_in[3];
    const float* dw_b       = (const float*)d_in[4];
    const float* pw_w       = (const float*)d_in[5];
    const float* pw_b       = (const float*)d_in[6];
    const float* ln_g       = (const float*)d_in[7];
    const float* ln_bb      = (const float*)d_in[8];
    const float* in_proj_w  = (const float*)d_in[9];
    const float* in_proj_b  = (const float*)d_in[10];
    const float* out_proj_w = (const float*)d_in[11];
    const float* out_proj_b = (const float*)d_in[12];
    const float* proj_w     = (const float*)d_in[13];
    const float* proj_b     = (const float*)d_in[14];
    const float* memory_bank= (const float*)d_in[15];
    const int*   mem_season = (const int*)d_in[16];
    const float* mem_year   = (const float*)d_in[17];

    float* out_final = (float*)d_out;
    float* q_out = out_final + (size_t)BB_ * NN * DD;

    float* ws = (float*)d_ws;
    size_t off = 0;
    float* QPRE  = ws + off; off += 1048576;
    float* QNORM = ws + off; off += 16;
    float* NRMP  = ws + off; off += 4 * MM;
    float* SIMP  = ws + off; off += 64 * MM;
    int*   TOPK  = (int*)(ws + off); off += 128;
    short* XH    = (short*)(ws + off); off += 524288;   // 1,048,576 bf16
    short* XL    = (short*)(ws + off); off += 524288;
    short* AH    = (short*)(ws + off); off += 16777216; // 33,554,432 bf16
    short* AL    = (short*)(ws + off); off += 16777216;
    bool use_pre = (ws_size >= off * 4);

    // attention buffers alias the AH region (k2 is done with AH before these run)
    short* WQKV16 = AH;                      // 49,152
    short* WC16   = AH + 49152;              // 16,384
    float* BC     = (float*)(AH + 65536);    // 128 f32 (256 shorts)
    short* QH16   = AH + 66048;              // 1,048,576
    short* KH16   = QH16 + 1048576;          // 8,388,608
    short* VH16   = KH16 + 8388608;          // 8,388,608
    short* CTX16  = VH16 + 8388608;          // 1,048,576

    k1_conv<<<dim3(8, 16), 256, 0, stream>>>(x_scalar, dw_w, dw_b, XH, XL);
    if (use_pre) {
        k0_cvt2<<<16384, 256, 0, stream>>>(pw_w, AH, AL);
        k2_split<true><<<8192, 256, 0, stream>>>(pw_w, AH, AL, pw_b, XH, XL, QPRE);
    } else {
        k2_split<false><<<8192, 256, 0, stream>>>(pw_w, nullptr, nullptr, pw_b, XH, XL, QPRE);
    }
    k3_ln<<<2048, 256, 0, stream>>>(QPRE, ln_g, ln_bb, q_out);
    k3b_qnorm<<<16, 256, 0, stream>>>(q_out, QNORM);
    k4_sim<<<dim3(299, 4), 256, 0, stream>>>(memory_bank, q_out, SIMP, NRMP);
    k5_topk<<<16, 256, 0, stream>>>(SIMP, NRMP, QNORM, season_q, year_q, mem_season, mem_year, TOPK);
    if (use_pre) {
        k6w<<<1, 256, 0, stream>>>(in_proj_w, out_proj_w, out_proj_b, proj_w, proj_b, WQKV16, WC16, BC);
        k6q<<<dim3(4, 16), 256, 0, stream>>>(q_out, WQKV16, in_proj_b, QH16);
        k6kv<<<dim3(32, 16), 256, 0, stream>>>(memory_bank, TOPK, WQKV16, in_proj_b, KH16, VH16);
        k6s<<<dim3(64, 16), 256, 0, stream>>>(QH16, KH16, VH16, CTX16);
        k6f<<<64, 256, 0, stream>>>(CTX16, WC16, BC, out_final);
    } else {
        k6_attn<<<dim3(128, 16), 256, 0, stream>>>(memory_bank, q_out, TOPK, in_proj_w, in_proj_b,
                                                   out_proj_w, out_proj_b, proj_w, proj_b, out_final);
    }
}